// Round 6
// baseline (86.178 us; speedup 1.0000x reference)
//
#include <hip/hip_runtime.h>
#include <math.h>

#define NN 8192
#define FF 128
#define CAP 128

typedef float nfloat4 __attribute__((ext_vector_type(4)));

// --- per-row attention dots: f1[i] = x[i]·a[0:128], f2[i] = x[i]·a[128:256]
__global__ __launch_bounds__(256) void k_scores(const float* __restrict__ x,
                                                const float* __restrict__ a,
                                                float* __restrict__ f1,
                                                float* __restrict__ f2) {
  int gid = blockIdx.x * blockDim.x + threadIdx.x;
  int row = gid >> 6;
  int lane = gid & 63;
  if (row >= NN) return;
  const float* xr = x + (size_t)row * FF;
  float v0 = xr[lane], v1 = xr[lane + 64];
  float s1 = v0 * a[lane] + v1 * a[lane + 64];
  float s2 = v0 * a[FF + lane] + v1 * a[FF + lane + 64];
  #pragma unroll
  for (int off = 32; off > 0; off >>= 1) {
    s1 += __shfl_down(s1, off);
    s2 += __shfl_down(s2, off);
  }
  if (lane == 0) { f1[row] = s1; f2[row] = s2; }
}

// --- stream+compact+softmax: adj row -> nnz, cols (coalesced), vals, rowsum
__global__ __launch_bounds__(256) void k_scan(const float* __restrict__ adj,
                                              const float* __restrict__ f1g,
                                              const float* __restrict__ f2g,
                                              int* __restrict__ nnzg,
                                              int* __restrict__ colsg,
                                              float* __restrict__ valsg,
                                              float* __restrict__ rowsumg) {
  const int row = blockIdx.x;
  const int t = threadIdx.x;
  const int lane = t & 63, w = t >> 6;
  __shared__ int s_cnt[32];
  __shared__ int s_cols[CAP];

  const nfloat4* arow = (const nfloat4*)(adj + (size_t)row * NN);
  unsigned msk[8];
  int within[8];
  const unsigned long long lt = (1ull << lane) - 1ull;
  #pragma unroll
  for (int it = 0; it < 8; ++it) {
    nfloat4 v = __builtin_nontemporal_load(&arow[it * 256 + t]);
    bool c0 = v.x > 0.f, c1 = v.y > 0.f, c2 = v.z > 0.f, c3 = v.w > 0.f;
    unsigned long long b0 = __ballot(c0), b1 = __ballot(c1),
                       b2 = __ballot(c2), b3 = __ballot(c3);
    within[it] = __popcll(b0 & lt) + __popcll(b1 & lt) +
                 __popcll(b2 & lt) + __popcll(b3 & lt);
    msk[it] = (c0 ? 1u : 0u) | (c1 ? 2u : 0u) | (c2 ? 4u : 0u) | (c3 ? 8u : 0u);
    if (lane == 0)
      s_cnt[it * 4 + w] = __popcll(b0) + __popcll(b1) + __popcll(b2) + __popcll(b3);
  }
  __syncthreads();

  int base[8];
  int run = 0;
  #pragma unroll
  for (int it = 0; it < 8; ++it) {
    #pragma unroll
    for (int ww = 0; ww < 4; ++ww) {
      if (ww == w) base[it] = run;
      run += s_cnt[it * 4 + ww];
    }
  }
  const int cnt = run < CAP ? run : CAP;

  #pragma unroll
  for (int it = 0; it < 8; ++it) {
    unsigned m = msk[it];
    if (m) {
      int pos = base[it] + within[it];
      int j0 = (it * 256 + t) * 4;
      if (m & 1u) { if (pos < CAP) s_cols[pos] = j0;     pos++; }
      if (m & 2u) { if (pos < CAP) s_cols[pos] = j0 + 1; pos++; }
      if (m & 4u) { if (pos < CAP) s_cols[pos] = j0 + 2; pos++; }
      if (m & 8u) { if (pos < CAP) s_cols[pos] = j0 + 3; pos++; }
    }
  }
  __syncthreads();

  // coalesced cols write
  if (t < cnt) colsg[(size_t)row * CAP + t] = s_cols[t];
  if (t == 0) nnzg[row] = cnt;

  // wave-0 softmax + rowsum + vals
  if (w == 0) {
    const float F1 = f1g[row];
    int i0 = lane, i1 = lane + 64;
    int col0 = (i0 < cnt) ? s_cols[i0] : 0;
    int col1 = (i1 < cnt) ? s_cols[i1] : 0;
    float e0 = -INFINITY, e1 = -INFINITY;
    if (i0 < cnt) { float s = F1 + f2g[col0]; e0 = s > 0.f ? s : 0.2f * s; }
    if (i1 < cnt) { float s = F1 + f2g[col1]; e1 = s > 0.f ? s : 0.2f * s; }
    float mx = fmaxf(e0, e1);
    #pragma unroll
    for (int off = 32; off > 0; off >>= 1) mx = fmaxf(mx, __shfl_xor(mx, off));
    float p0 = (i0 < cnt) ? expf(e0 - mx) : 0.f;
    float p1 = (i1 < cnt) ? expf(e1 - mx) : 0.f;
    float sm = p0 + p1;
    #pragma unroll
    for (int off = 32; off > 0; off >>= 1) sm += __shfl_xor(sm, off);
    float inv = 1.f / sm;
    float u0 = p0 * inv, u1 = p1 * inv;
    float q = u0 * u0 + u1 * u1;
    #pragma unroll
    for (int off = 32; off > 0; off >>= 1) q += __shfl_xor(q, off);
    if (lane == 0) rowsumg[row] = 0.5f * q;
    float* vg = valsg + (size_t)row * CAP;
    if (i0 < cnt) vg[i0] = u0;
    if (i1 < cnt) vg[i1] = u1;
  }
}

// --- one wave per row: pure SpMM U@x + forward lifting
__global__ __launch_bounds__(256) void k_fwd(
    const float* __restrict__ x, const float* __restrict__ temp,
    const int* __restrict__ nnzg, const int* __restrict__ colsg,
    const float* __restrict__ valsg, const float* __restrict__ rowsumg,
    float* __restrict__ featg) {
  const int wl = threadIdx.x >> 6;
  const int lane = threadIdx.x & 63;
  const int row = blockIdx.x * 4 + wl;

  __shared__ int   s_c[4][CAP];
  __shared__ float s_u[4][CAP];

  const int cnt = nnzg[row];
  const int* cg = colsg + (size_t)row * CAP;
  const float* vg = valsg + (size_t)row * CAP;
  const int i0 = lane, i1 = lane + 64;
  if (i0 < cnt) { s_c[wl][i0] = __builtin_nontemporal_load(cg + i0);
                  s_u[wl][i0] = __builtin_nontemporal_load(vg + i0); }
  if (i1 < cnt) { s_c[wl][i1] = __builtin_nontemporal_load(cg + i1);
                  s_u[wl][i1] = __builtin_nontemporal_load(vg + i1); }
  __syncthreads();

  float acc0 = 0.f, acc1 = 0.f;
  int k = 0;
  for (; k + 3 < cnt; k += 4) {
    int   c0 = s_c[wl][k],   c1 = s_c[wl][k+1], c2 = s_c[wl][k+2], c3 = s_c[wl][k+3];
    float w0 = s_u[wl][k],   w1 = s_u[wl][k+1], w2 = s_u[wl][k+2], w3 = s_u[wl][k+3];
    float a0 = x[(size_t)c0 * FF + lane],      b0 = x[(size_t)c0 * FF + lane + 64];
    float a1 = x[(size_t)c1 * FF + lane],      b1 = x[(size_t)c1 * FF + lane + 64];
    float a2 = x[(size_t)c2 * FF + lane],      b2 = x[(size_t)c2 * FF + lane + 64];
    float a3 = x[(size_t)c3 * FF + lane],      b3 = x[(size_t)c3 * FF + lane + 64];
    acc0 += w0 * a0 + w1 * a1 + w2 * a2 + w3 * a3;
    acc1 += w0 * b0 + w1 * b1 + w2 * b2 + w3 * b3;
  }
  for (; k < cnt; ++k) {
    int c = s_c[wl][k]; float u = s_u[wl][k];
    acc0 += u * x[(size_t)c * FF + lane];
    acc1 += u * x[(size_t)c * FF + lane + 64];
  }

  const float rs = rowsumg[row];
  const float coe2 = 1.f / (1.f + expf(-temp[2]));
  float xv0 = x[(size_t)row * FF + lane];
  float xv1 = x[(size_t)row * FF + lane + 64];
  featg[(size_t)row * FF + lane]      = acc0 - xv0 * rs + (1.f - coe2) * xv0;
  featg[(size_t)row * FF + lane + 64] = acc1 - xv1 * rs + (1.f - coe2) * xv1;
}

// --- one wave per row: SpMM U@feat + inverse lifting + output blend
__global__ __launch_bounds__(256) void k_bwd(
    const float* __restrict__ featg, const float* __restrict__ h0,
    const float* __restrict__ temp,
    const int* __restrict__ nnzg, const int* __restrict__ colsg,
    const float* __restrict__ valsg, const float* __restrict__ rowsumg,
    float* __restrict__ out) {
  const int wl = threadIdx.x >> 6;
  const int lane = threadIdx.x & 63;
  const int row = blockIdx.x * 4 + wl;

  __shared__ int   s_c[4][CAP];
  __shared__ float s_u[4][CAP];

  const int cnt = nnzg[row];
  const int* cg = colsg + (size_t)row * CAP;
  const float* vg = valsg + (size_t)row * CAP;
  const int i0 = lane, i1 = lane + 64;
  if (i0 < cnt) { s_c[wl][i0] = __builtin_nontemporal_load(cg + i0);
                  s_u[wl][i0] = __builtin_nontemporal_load(vg + i0); }
  if (i1 < cnt) { s_c[wl][i1] = __builtin_nontemporal_load(cg + i1);
                  s_u[wl][i1] = __builtin_nontemporal_load(vg + i1); }
  __syncthreads();

  float acc0 = 0.f, acc1 = 0.f;
  int k = 0;
  for (; k + 3 < cnt; k += 4) {
    int   c0 = s_c[wl][k],   c1 = s_c[wl][k+1], c2 = s_c[wl][k+2], c3 = s_c[wl][k+3];
    float w0 = s_u[wl][k],   w1 = s_u[wl][k+1], w2 = s_u[wl][k+2], w3 = s_u[wl][k+3];
    float a0 = featg[(size_t)c0 * FF + lane],  b0 = featg[(size_t)c0 * FF + lane + 64];
    float a1 = featg[(size_t)c1 * FF + lane],  b1 = featg[(size_t)c1 * FF + lane + 64];
    float a2 = featg[(size_t)c2 * FF + lane],  b2 = featg[(size_t)c2 * FF + lane + 64];
    float a3 = featg[(size_t)c3 * FF + lane],  b3 = featg[(size_t)c3 * FF + lane + 64];
    acc0 += w0 * a0 + w1 * a1 + w2 * a2 + w3 * a3;
    acc1 += w0 * b0 + w1 * b1 + w2 * b2 + w3 * b3;
  }
  for (; k < cnt; ++k) {
    int c = s_c[wl][k]; float u = s_u[wl][k];
    acc0 += u * featg[(size_t)c * FF + lane];
    acc1 += u * featg[(size_t)c * FF + lane + 64];
  }

  const float rs = rowsumg[row];
  const float coe1 = 1.f / (1.f + expf(-temp[1]));
  const float coe3 = 1.f / (1.f + expf(-temp[3]));
  float ft0 = featg[(size_t)row * FF + lane];
  float ft1 = featg[(size_t)row * FF + lane + 64];
  float odd0 = ft0 - acc0, odd1 = ft1 - acc1;
  float ev0 = coe3 * acc0 + odd0 * rs;
  float ev1 = coe3 * acc1 + odd1 * rs;
  float fp0 = coe1 * ev0 + (1.f - coe1) * odd0;
  float fp1 = coe1 * ev1 + (1.f - coe1) * odd1;
  float h00 = __builtin_nontemporal_load(h0 + (size_t)row * FF + lane);
  float h01 = __builtin_nontemporal_load(h0 + (size_t)row * FF + lane + 64);
  __builtin_nontemporal_store(0.2f * fp0 + 0.8f * h00, out + (size_t)row * FF + lane);
  __builtin_nontemporal_store(0.2f * fp1 + 0.8f * h01, out + (size_t)row * FF + lane + 64);
}

extern "C" void kernel_launch(void* const* d_in, const int* in_sizes, int n_in,
                              void* d_out, int out_size, void* d_ws, size_t ws_size,
                              hipStream_t stream) {
  const float* x    = (const float*)d_in[0];
  const float* h0   = (const float*)d_in[1];
  const float* adj  = (const float*)d_in[2];
  const float* a    = (const float*)d_in[3];
  const float* temp = (const float*)d_in[4];
  float* out = (float*)d_out;

  float* f1 = (float*)d_ws;
  float* f2 = f1 + NN;
  float* rowsum = f2 + NN;
  int*   nnz = (int*)(rowsum + NN);
  int*   cols = nnz + NN;
  float* vals = (float*)(cols + (size_t)NN * CAP);
  float* feat = vals + (size_t)NN * CAP;

  k_scores<<<NN / 4, 256, 0, stream>>>(x, a, f1, f2);
  k_scan<<<NN, 256, 0, stream>>>(adj, f1, f2, nnz, cols, vals, rowsum);
  k_fwd<<<NN / 4, 256, 0, stream>>>(x, temp, nnz, cols, vals, rowsum, feat);
  k_bwd<<<NN / 4, 256, 0, stream>>>(feat, h0, temp, nnz, cols, vals, rowsum, out);
}

// Round 7
// 81.745 us; speedup vs baseline: 1.0542x; 1.0542x over previous
//
#include <hip/hip_runtime.h>
#include <math.h>

#define NN 8192
#define FF 128
#define CAP 128

typedef float nfloat4 __attribute__((ext_vector_type(4)));

// --- per-row attention dots: f1[i] = x[i]·a[0:128], f2[i] = x[i]·a[128:256]
__global__ __launch_bounds__(256) void k_scores(const float* __restrict__ x,
                                                const float* __restrict__ a,
                                                float* __restrict__ f1,
                                                float* __restrict__ f2) {
  int gid = blockIdx.x * blockDim.x + threadIdx.x;
  int row = gid >> 6;
  int lane = gid & 63;
  if (row >= NN) return;
  const float* xr = x + (size_t)row * FF;
  float v0 = xr[lane], v1 = xr[lane + 64];
  float s1 = v0 * a[lane] + v1 * a[lane + 64];
  float s2 = v0 * a[FF + lane] + v1 * a[FF + lane + 64];
  #pragma unroll
  for (int off = 32; off > 0; off >>= 1) {
    s1 += __shfl_down(s1, off);
    s2 += __shfl_down(s2, off);
  }
  if (lane == 0) { f1[row] = s1; f2[row] = s2; }
}

// --- wave-per-row: stream adj row (32-deep MLP), wave-local ballot compaction,
//     wave softmax, fused fwd SpMM U@x + forward lifting. No cross-wave coupling.
__global__ __launch_bounds__(256) void k_scanfwd(
    const float* __restrict__ adj, const float* __restrict__ x,
    const float* __restrict__ f1g, const float* __restrict__ f2g,
    const float* __restrict__ temp,
    int* __restrict__ nnzg, int* __restrict__ colsg, float* __restrict__ valsg,
    float* __restrict__ rowsumg, float* __restrict__ featg) {
  const int w = threadIdx.x >> 6;
  const int lane = threadIdx.x & 63;
  const int row = blockIdx.x * 4 + w;

  __shared__ int   s_c[4][CAP];
  __shared__ float s_u[4][CAP];

  // ---- stream one 32KB row per wave; wave-local deterministic compaction ----
  const nfloat4* arow = (const nfloat4*)(adj + (size_t)row * NN);
  const unsigned long long lt = (1ull << lane) - 1ull;
  int run = 0;
  #pragma unroll 8
  for (int it = 0; it < 32; ++it) {
    nfloat4 v = __builtin_nontemporal_load(&arow[it * 64 + lane]);
    bool c0 = v.x > 0.f, c1 = v.y > 0.f, c2 = v.z > 0.f, c3 = v.w > 0.f;
    unsigned long long b0 = __ballot(c0), b1 = __ballot(c1),
                       b2 = __ballot(c2), b3 = __ballot(c3);
    int pos = run + __popcll(b0 & lt) + __popcll(b1 & lt) +
                    __popcll(b2 & lt) + __popcll(b3 & lt);
    int j0 = (it * 64 + lane) * 4;
    if (c0) { if (pos < CAP) s_c[w][pos] = j0;     pos++; }
    if (c1) { if (pos < CAP) s_c[w][pos] = j0 + 1; pos++; }
    if (c2) { if (pos < CAP) s_c[w][pos] = j0 + 2; pos++; }
    if (c3) { if (pos < CAP) s_c[w][pos] = j0 + 3; pos++; }
    run += __popcll(b0) + __popcll(b1) + __popcll(b2) + __popcll(b3);
  }
  const int cnt = run < CAP ? run : CAP;
  __syncthreads();   // orders LDS scatter before reads (waves are skew-aligned)

  // ---- wave softmax + rowsum + persist sparse row ----
  const float F1 = f1g[row];
  const int i0 = lane, i1 = lane + 64;
  int col0 = (i0 < cnt) ? s_c[w][i0] : 0;
  int col1 = (i1 < cnt) ? s_c[w][i1] : 0;
  float e0 = -INFINITY, e1 = -INFINITY;
  if (i0 < cnt) { float s = F1 + f2g[col0]; e0 = s > 0.f ? s : 0.2f * s; }
  if (i1 < cnt) { float s = F1 + f2g[col1]; e1 = s > 0.f ? s : 0.2f * s; }
  float mx = fmaxf(e0, e1);
  #pragma unroll
  for (int off = 32; off > 0; off >>= 1) mx = fmaxf(mx, __shfl_xor(mx, off));
  float p0 = (i0 < cnt) ? expf(e0 - mx) : 0.f;
  float p1 = (i1 < cnt) ? expf(e1 - mx) : 0.f;
  float sm = p0 + p1;
  #pragma unroll
  for (int off = 32; off > 0; off >>= 1) sm += __shfl_xor(sm, off);
  float inv = 1.f / sm;
  float u0 = p0 * inv, u1 = p1 * inv;
  float q = u0 * u0 + u1 * u1;
  #pragma unroll
  for (int off = 32; off > 0; off >>= 1) q += __shfl_xor(q, off);
  const float rs = 0.5f * q;

  if (i0 < cnt) { s_u[w][i0] = u0; colsg[(size_t)row * CAP + i0] = col0;
                  valsg[(size_t)row * CAP + i0] = u0; }
  if (i1 < cnt) { s_u[w][i1] = u1; colsg[(size_t)row * CAP + i1] = col1;
                  valsg[(size_t)row * CAP + i1] = u1; }
  if (lane == 0) { nnzg[row] = cnt; rowsumg[row] = rs; }

  // ---- fwd SpMM: 8 entries/round, 16 gather loads in flight ----
  float acc0 = 0.f, acc1 = 0.f;
  int k = 0;
  for (; k + 7 < cnt; k += 8) {
    int   c0 = s_c[w][k],   c1 = s_c[w][k+1], c2 = s_c[w][k+2], c3 = s_c[w][k+3];
    int   c4 = s_c[w][k+4], c5 = s_c[w][k+5], c6 = s_c[w][k+6], c7 = s_c[w][k+7];
    float w0 = s_u[w][k],   w1 = s_u[w][k+1], w2 = s_u[w][k+2], w3 = s_u[w][k+3];
    float w4 = s_u[w][k+4], w5 = s_u[w][k+5], w6 = s_u[w][k+6], w7 = s_u[w][k+7];
    float a0 = x[(size_t)c0 * FF + lane],      b0 = x[(size_t)c0 * FF + lane + 64];
    float a1 = x[(size_t)c1 * FF + lane],      b1 = x[(size_t)c1 * FF + lane + 64];
    float a2 = x[(size_t)c2 * FF + lane],      b2 = x[(size_t)c2 * FF + lane + 64];
    float a3 = x[(size_t)c3 * FF + lane],      b3 = x[(size_t)c3 * FF + lane + 64];
    float a4 = x[(size_t)c4 * FF + lane],      b4 = x[(size_t)c4 * FF + lane + 64];
    float a5 = x[(size_t)c5 * FF + lane],      b5 = x[(size_t)c5 * FF + lane + 64];
    float a6 = x[(size_t)c6 * FF + lane],      b6 = x[(size_t)c6 * FF + lane + 64];
    float a7 = x[(size_t)c7 * FF + lane],      b7 = x[(size_t)c7 * FF + lane + 64];
    acc0 += w0*a0 + w1*a1 + w2*a2 + w3*a3 + w4*a4 + w5*a5 + w6*a6 + w7*a7;
    acc1 += w0*b0 + w1*b1 + w2*b2 + w3*b3 + w4*b4 + w5*b5 + w6*b6 + w7*b7;
  }
  for (; k < cnt; ++k) {
    int c = s_c[w][k]; float u = s_u[w][k];
    acc0 += u * x[(size_t)c * FF + lane];
    acc1 += u * x[(size_t)c * FF + lane + 64];
  }

  const float coe2 = 1.f / (1.f + expf(-temp[2]));
  float xv0 = x[(size_t)row * FF + lane];
  float xv1 = x[(size_t)row * FF + lane + 64];
  featg[(size_t)row * FF + lane]      = acc0 - xv0 * rs + (1.f - coe2) * xv0;
  featg[(size_t)row * FF + lane + 64] = acc1 - xv1 * rs + (1.f - coe2) * xv1;
}

// --- one wave per row: SpMM U@feat (8-unroll) + inverse lifting + output blend
__global__ __launch_bounds__(256) void k_bwd(
    const float* __restrict__ featg, const float* __restrict__ h0,
    const float* __restrict__ temp,
    const int* __restrict__ nnzg, const int* __restrict__ colsg,
    const float* __restrict__ valsg, const float* __restrict__ rowsumg,
    float* __restrict__ out) {
  const int wl = threadIdx.x >> 6;
  const int lane = threadIdx.x & 63;
  const int row = blockIdx.x * 4 + wl;

  __shared__ int   s_c[4][CAP];
  __shared__ float s_u[4][CAP];

  const int cnt = nnzg[row];
  const int* cg = colsg + (size_t)row * CAP;
  const float* vg = valsg + (size_t)row * CAP;
  const int i0 = lane, i1 = lane + 64;
  if (i0 < cnt) { s_c[wl][i0] = cg[i0]; s_u[wl][i0] = vg[i0]; }
  if (i1 < cnt) { s_c[wl][i1] = cg[i1]; s_u[wl][i1] = vg[i1]; }
  __syncthreads();

  float acc0 = 0.f, acc1 = 0.f;
  int k = 0;
  for (; k + 7 < cnt; k += 8) {
    int   c0 = s_c[wl][k],   c1 = s_c[wl][k+1], c2 = s_c[wl][k+2], c3 = s_c[wl][k+3];
    int   c4 = s_c[wl][k+4], c5 = s_c[wl][k+5], c6 = s_c[wl][k+6], c7 = s_c[wl][k+7];
    float w0 = s_u[wl][k],   w1 = s_u[wl][k+1], w2 = s_u[wl][k+2], w3 = s_u[wl][k+3];
    float w4 = s_u[wl][k+4], w5 = s_u[wl][k+5], w6 = s_u[wl][k+6], w7 = s_u[wl][k+7];
    float a0 = featg[(size_t)c0 * FF + lane],  b0 = featg[(size_t)c0 * FF + lane + 64];
    float a1 = featg[(size_t)c1 * FF + lane],  b1 = featg[(size_t)c1 * FF + lane + 64];
    float a2 = featg[(size_t)c2 * FF + lane],  b2 = featg[(size_t)c2 * FF + lane + 64];
    float a3 = featg[(size_t)c3 * FF + lane],  b3 = featg[(size_t)c3 * FF + lane + 64];
    float a4 = featg[(size_t)c4 * FF + lane],  b4 = featg[(size_t)c4 * FF + lane + 64];
    float a5 = featg[(size_t)c5 * FF + lane],  b5 = featg[(size_t)c5 * FF + lane + 64];
    float a6 = featg[(size_t)c6 * FF + lane],  b6 = featg[(size_t)c6 * FF + lane + 64];
    float a7 = featg[(size_t)c7 * FF + lane],  b7 = featg[(size_t)c7 * FF + lane + 64];
    acc0 += w0*a0 + w1*a1 + w2*a2 + w3*a3 + w4*a4 + w5*a5 + w6*a6 + w7*a7;
    acc1 += w0*b0 + w1*b1 + w2*b2 + w3*b3 + w4*b4 + w5*b5 + w6*b6 + w7*b7;
  }
  for (; k < cnt; ++k) {
    int c = s_c[wl][k]; float u = s_u[wl][k];
    acc0 += u * featg[(size_t)c * FF + lane];
    acc1 += u * featg[(size_t)c * FF + lane + 64];
  }

  const float rs = rowsumg[row];
  const float coe1 = 1.f / (1.f + expf(-temp[1]));
  const float coe3 = 1.f / (1.f + expf(-temp[3]));
  float ft0 = featg[(size_t)row * FF + lane];
  float ft1 = featg[(size_t)row * FF + lane + 64];
  float odd0 = ft0 - acc0, odd1 = ft1 - acc1;
  float ev0 = coe3 * acc0 + odd0 * rs;
  float ev1 = coe3 * acc1 + odd1 * rs;
  float fp0 = coe1 * ev0 + (1.f - coe1) * odd0;
  float fp1 = coe1 * ev1 + (1.f - coe1) * odd1;
  float h00 = __builtin_nontemporal_load(h0 + (size_t)row * FF + lane);
  float h01 = __builtin_nontemporal_load(h0 + (size_t)row * FF + lane + 64);
  __builtin_nontemporal_store(0.2f * fp0 + 0.8f * h00, out + (size_t)row * FF + lane);
  __builtin_nontemporal_store(0.2f * fp1 + 0.8f * h01, out + (size_t)row * FF + lane + 64);
}

extern "C" void kernel_launch(void* const* d_in, const int* in_sizes, int n_in,
                              void* d_out, int out_size, void* d_ws, size_t ws_size,
                              hipStream_t stream) {
  const float* x    = (const float*)d_in[0];
  const float* h0   = (const float*)d_in[1];
  const float* adj  = (const float*)d_in[2];
  const float* a    = (const float*)d_in[3];
  const float* temp = (const float*)d_in[4];
  float* out = (float*)d_out;

  float* f1 = (float*)d_ws;
  float* f2 = f1 + NN;
  float* rowsum = f2 + NN;
  int*   nnz = (int*)(rowsum + NN);
  int*   cols = nnz + NN;
  float* vals = (float*)(cols + (size_t)NN * CAP);
  float* feat = vals + (size_t)NN * CAP;

  k_scores<<<NN / 4, 256, 0, stream>>>(x, a, f1, f2);
  k_scanfwd<<<NN / 4, 256, 0, stream>>>(adj, x, f1, f2, temp, nnz, cols, vals, rowsum, feat);
  k_bwd<<<NN / 4, 256, 0, stream>>>(feat, h0, temp, nnz, cols, vals, rowsum, out);
}

// Round 9
// 75.905 us; speedup vs baseline: 1.1353x; 1.0769x over previous
//
#include <hip/hip_runtime.h>
#include <math.h>

#define NN 8192
#define FF 128
#define CAP 128

typedef float nfloat4 __attribute__((ext_vector_type(4)));
typedef float nfloat2 __attribute__((ext_vector_type(2)));

__device__ __forceinline__ unsigned short f2bf(float f) {
  unsigned u = __float_as_uint(f);
  return (unsigned short)((u + 0x7fffu + ((u >> 16) & 1u)) >> 16);
}

// --- per-row dots f1,f2 + bf16-packed x table (features 2*lane, 2*lane+1)
__global__ __launch_bounds__(256) void k_scores(const float* __restrict__ x,
                                                const float* __restrict__ a,
                                                float* __restrict__ f1,
                                                float* __restrict__ f2,
                                                unsigned* __restrict__ xb) {
  const int w = threadIdx.x >> 6;
  const int lane = threadIdx.x & 63;
  const int row = blockIdx.x * 4 + w;
  float2 v = ((const float2*)(x + (size_t)row * FF))[lane];
  float2 A1 = ((const float2*)a)[lane];
  float2 A2 = ((const float2*)(a + FF))[lane];
  float s1 = v.x * A1.x + v.y * A1.y;
  float s2 = v.x * A2.x + v.y * A2.y;
  #pragma unroll
  for (int off = 32; off > 0; off >>= 1) {
    s1 += __shfl_down(s1, off);
    s2 += __shfl_down(s2, off);
  }
  if (lane == 0) { f1[row] = s1; f2[row] = s2; }
  unsigned pk = (unsigned)f2bf(v.x) | ((unsigned)f2bf(v.y) << 16);
  xb[(size_t)row * 64 + lane] = pk;
}

// --- wave-per-row: stream adj row, ballot compaction, wave softmax,
//     fused fwd SpMM over bf16 x table + forward lifting. No barriers.
__global__ __launch_bounds__(256) void k_scanfwd(
    const float* __restrict__ adj, const float* __restrict__ x,
    const unsigned* __restrict__ xb,
    const float* __restrict__ f1g, const float* __restrict__ f2g,
    const float* __restrict__ temp,
    int* __restrict__ nnzg, int* __restrict__ colsg, float* __restrict__ valsg,
    float* __restrict__ rowsumg, float* __restrict__ featg,
    unsigned* __restrict__ featb) {
  const int w = threadIdx.x >> 6;
  const int lane = threadIdx.x & 63;
  const int row = blockIdx.x * 4 + w;

  __shared__ int   s_c[4][CAP];
  __shared__ float s_u[4][CAP];

  // ---- stream one 32KB row per wave; wave-local deterministic compaction ----
  const nfloat4* arow = (const nfloat4*)(adj + (size_t)row * NN);
  const unsigned long long lt = (1ull << lane) - 1ull;
  int run = 0;
  #pragma unroll 8
  for (int it = 0; it < 32; ++it) {
    nfloat4 v = __builtin_nontemporal_load(&arow[it * 64 + lane]);
    bool c0 = v.x > 0.f, c1 = v.y > 0.f, c2 = v.z > 0.f, c3 = v.w > 0.f;
    unsigned long long b0 = __ballot(c0), b1 = __ballot(c1),
                       b2 = __ballot(c2), b3 = __ballot(c3);
    int pos = run + __popcll(b0 & lt) + __popcll(b1 & lt) +
                    __popcll(b2 & lt) + __popcll(b3 & lt);
    int j0 = (it * 64 + lane) * 4;
    if (c0) { if (pos < CAP) s_c[w][pos] = j0;     pos++; }
    if (c1) { if (pos < CAP) s_c[w][pos] = j0 + 1; pos++; }
    if (c2) { if (pos < CAP) s_c[w][pos] = j0 + 2; pos++; }
    if (c3) { if (pos < CAP) s_c[w][pos] = j0 + 3; pos++; }
    run += __popcll(b0) + __popcll(b1) + __popcll(b2) + __popcll(b3);
  }
  const int cnt = run < CAP ? run : CAP;

  // ---- wave softmax + rowsum + persist sparse row (same-wave LDS, no barrier) ----
  const float F1 = f1g[row];
  const int i0 = lane, i1 = lane + 64;
  int col0 = (i0 < cnt) ? s_c[w][i0] : 0;
  int col1 = (i1 < cnt) ? s_c[w][i1] : 0;
  float e0 = -INFINITY, e1 = -INFINITY;
  if (i0 < cnt) { float s = F1 + f2g[col0]; e0 = s > 0.f ? s : 0.2f * s; }
  if (i1 < cnt) { float s = F1 + f2g[col1]; e1 = s > 0.f ? s : 0.2f * s; }
  float mx = fmaxf(e0, e1);
  #pragma unroll
  for (int off = 32; off > 0; off >>= 1) mx = fmaxf(mx, __shfl_xor(mx, off));
  float p0 = (i0 < cnt) ? expf(e0 - mx) : 0.f;
  float p1 = (i1 < cnt) ? expf(e1 - mx) : 0.f;
  float sm = p0 + p1;
  #pragma unroll
  for (int off = 32; off > 0; off >>= 1) sm += __shfl_xor(sm, off);
  float inv = 1.f / sm;
  float u0 = p0 * inv, u1 = p1 * inv;
  float q = u0 * u0 + u1 * u1;
  #pragma unroll
  for (int off = 32; off > 0; off >>= 1) q += __shfl_xor(q, off);
  const float rs = 0.5f * q;

  if (i0 < cnt) { s_u[w][i0] = u0; colsg[(size_t)row * CAP + i0] = col0;
                  valsg[(size_t)row * CAP + i0] = u0; }
  if (i1 < cnt) { s_u[w][i1] = u1; colsg[(size_t)row * CAP + i1] = col1;
                  valsg[(size_t)row * CAP + i1] = u1; }
  if (lane == 0) { nnzg[row] = cnt; rowsumg[row] = rs; }

  // ---- fwd SpMM over bf16 x table: 8 gathers (one uint each) in flight ----
  float acc0 = 0.f, acc1 = 0.f;
  int k = 0;
  for (; k + 7 < cnt; k += 8) {
    int   c0 = s_c[w][k],   c1 = s_c[w][k+1], c2 = s_c[w][k+2], c3 = s_c[w][k+3];
    int   c4 = s_c[w][k+4], c5 = s_c[w][k+5], c6 = s_c[w][k+6], c7 = s_c[w][k+7];
    float w0 = s_u[w][k],   w1 = s_u[w][k+1], w2 = s_u[w][k+2], w3 = s_u[w][k+3];
    float w4 = s_u[w][k+4], w5 = s_u[w][k+5], w6 = s_u[w][k+6], w7 = s_u[w][k+7];
    unsigned g0 = xb[(size_t)c0 * 64 + lane], g1 = xb[(size_t)c1 * 64 + lane];
    unsigned g2 = xb[(size_t)c2 * 64 + lane], g3 = xb[(size_t)c3 * 64 + lane];
    unsigned g4 = xb[(size_t)c4 * 64 + lane], g5 = xb[(size_t)c5 * 64 + lane];
    unsigned g6 = xb[(size_t)c6 * 64 + lane], g7 = xb[(size_t)c7 * 64 + lane];
    acc0 += w0 * __uint_as_float(g0 << 16) + w1 * __uint_as_float(g1 << 16)
          + w2 * __uint_as_float(g2 << 16) + w3 * __uint_as_float(g3 << 16)
          + w4 * __uint_as_float(g4 << 16) + w5 * __uint_as_float(g5 << 16)
          + w6 * __uint_as_float(g6 << 16) + w7 * __uint_as_float(g7 << 16);
    acc1 += w0 * __uint_as_float(g0 & 0xffff0000u) + w1 * __uint_as_float(g1 & 0xffff0000u)
          + w2 * __uint_as_float(g2 & 0xffff0000u) + w3 * __uint_as_float(g3 & 0xffff0000u)
          + w4 * __uint_as_float(g4 & 0xffff0000u) + w5 * __uint_as_float(g5 & 0xffff0000u)
          + w6 * __uint_as_float(g6 & 0xffff0000u) + w7 * __uint_as_float(g7 & 0xffff0000u);
  }
  for (; k < cnt; ++k) {
    int c = s_c[w][k]; float u = s_u[w][k];
    unsigned g = xb[(size_t)c * 64 + lane];
    acc0 += u * __uint_as_float(g << 16);
    acc1 += u * __uint_as_float(g & 0xffff0000u);
  }

  const float coe2 = 1.f / (1.f + expf(-temp[2]));
  float2 xv = ((const float2*)(x + (size_t)row * FF))[lane];
  float ft0 = acc0 - xv.x * rs + (1.f - coe2) * xv.x;
  float ft1 = acc1 - xv.y * rs + (1.f - coe2) * xv.y;
  float2 ftv; ftv.x = ft0; ftv.y = ft1;
  ((float2*)featg)[(size_t)row * 64 + lane] = ftv;
  featb[(size_t)row * 64 + lane] = (unsigned)f2bf(ft0) | ((unsigned)f2bf(ft1) << 16);
}

// --- wave-per-row: SpMM U@feat (bf16 table) + inverse lifting + blend
__global__ __launch_bounds__(256) void k_bwd(
    const float* __restrict__ featg, const unsigned* __restrict__ featb,
    const float* __restrict__ h0, const float* __restrict__ temp,
    const int* __restrict__ nnzg, const int* __restrict__ colsg,
    const float* __restrict__ valsg, const float* __restrict__ rowsumg,
    float* __restrict__ out) {
  const int w = threadIdx.x >> 6;
  const int lane = threadIdx.x & 63;
  const int row = blockIdx.x * 4 + w;

  __shared__ int   s_c[4][CAP];
  __shared__ float s_u[4][CAP];

  const int cnt = nnzg[row];
  const int* cg = colsg + (size_t)row * CAP;
  const float* vg = valsg + (size_t)row * CAP;
  const int i0 = lane, i1 = lane + 64;
  if (i0 < cnt) { s_c[w][i0] = cg[i0]; s_u[w][i0] = vg[i0]; }
  if (i1 < cnt) { s_c[w][i1] = cg[i1]; s_u[w][i1] = vg[i1]; }

  float acc0 = 0.f, acc1 = 0.f;
  int k = 0;
  for (; k + 7 < cnt; k += 8) {
    int   c0 = s_c[w][k],   c1 = s_c[w][k+1], c2 = s_c[w][k+2], c3 = s_c[w][k+3];
    int   c4 = s_c[w][k+4], c5 = s_c[w][k+5], c6 = s_c[w][k+6], c7 = s_c[w][k+7];
    float w0 = s_u[w][k],   w1 = s_u[w][k+1], w2 = s_u[w][k+2], w3 = s_u[w][k+3];
    float w4 = s_u[w][k+4], w5 = s_u[w][k+5], w6 = s_u[w][k+6], w7 = s_u[w][k+7];
    unsigned g0 = featb[(size_t)c0 * 64 + lane], g1 = featb[(size_t)c1 * 64 + lane];
    unsigned g2 = featb[(size_t)c2 * 64 + lane], g3 = featb[(size_t)c3 * 64 + lane];
    unsigned g4 = featb[(size_t)c4 * 64 + lane], g5 = featb[(size_t)c5 * 64 + lane];
    unsigned g6 = featb[(size_t)c6 * 64 + lane], g7 = featb[(size_t)c7 * 64 + lane];
    acc0 += w0 * __uint_as_float(g0 << 16) + w1 * __uint_as_float(g1 << 16)
          + w2 * __uint_as_float(g2 << 16) + w3 * __uint_as_float(g3 << 16)
          + w4 * __uint_as_float(g4 << 16) + w5 * __uint_as_float(g5 << 16)
          + w6 * __uint_as_float(g6 << 16) + w7 * __uint_as_float(g7 << 16);
    acc1 += w0 * __uint_as_float(g0 & 0xffff0000u) + w1 * __uint_as_float(g1 & 0xffff0000u)
          + w2 * __uint_as_float(g2 & 0xffff0000u) + w3 * __uint_as_float(g3 & 0xffff0000u)
          + w4 * __uint_as_float(g4 & 0xffff0000u) + w5 * __uint_as_float(g5 & 0xffff0000u)
          + w6 * __uint_as_float(g6 & 0xffff0000u) + w7 * __uint_as_float(g7 & 0xffff0000u);
  }
  for (; k < cnt; ++k) {
    int c = s_c[w][k]; float u = s_u[w][k];
    unsigned g = featb[(size_t)c * 64 + lane];
    acc0 += u * __uint_as_float(g << 16);
    acc1 += u * __uint_as_float(g & 0xffff0000u);
  }

  const float rs = rowsumg[row];
  const float coe1 = 1.f / (1.f + expf(-temp[1]));
  const float coe3 = 1.f / (1.f + expf(-temp[3]));
  float2 ft = ((const float2*)featg)[(size_t)row * 64 + lane];
  float odd0 = ft.x - acc0, odd1 = ft.y - acc1;
  float ev0 = coe3 * acc0 + odd0 * rs;
  float ev1 = coe3 * acc1 + odd1 * rs;
  float fp0 = coe1 * ev0 + (1.f - coe1) * odd0;
  float fp1 = coe1 * ev1 + (1.f - coe1) * odd1;
  nfloat2 h = __builtin_nontemporal_load(((const nfloat2*)h0) + (size_t)row * 64 + lane);
  nfloat2 o;
  o.x = 0.2f * fp0 + 0.8f * h.x;
  o.y = 0.2f * fp1 + 0.8f * h.y;
  __builtin_nontemporal_store(o, ((nfloat2*)out) + (size_t)row * 64 + lane);
}

extern "C" void kernel_launch(void* const* d_in, const int* in_sizes, int n_in,
                              void* d_out, int out_size, void* d_ws, size_t ws_size,
                              hipStream_t stream) {
  const float* x    = (const float*)d_in[0];
  const float* h0   = (const float*)d_in[1];
  const float* adj  = (const float*)d_in[2];
  const float* a    = (const float*)d_in[3];
  const float* temp = (const float*)d_in[4];
  float* out = (float*)d_out;

  float* f1 = (float*)d_ws;                       // 32 KB
  float* f2 = f1 + NN;                            // 32 KB
  float* rowsum = f2 + NN;                        // 32 KB
  int*   nnz = (int*)(rowsum + NN);               // 32 KB
  int*   cols = nnz + NN;                         // 4 MB
  float* vals = (float*)(cols + (size_t)NN * CAP);// 4 MB
  float* feat = vals + (size_t)NN * CAP;          // 4 MB
  unsigned* xb = (unsigned*)(feat + (size_t)NN * FF);   // 2 MB
  unsigned* featb = xb + (size_t)NN * 64;               // 2 MB

  k_scores<<<NN / 4, 256, 0, stream>>>(x, a, f1, f2, xb);
  k_scanfwd<<<NN / 4, 256, 0, stream>>>(adj, x, xb, f1, f2, temp, nnz, cols, vals, rowsum, feat, featb);
  k_bwd<<<NN / 4, 256, 0, stream>>>(feat, featb, h0, temp, nnz, cols, vals, rowsum, out);
}

// Round 10
// 73.834 us; speedup vs baseline: 1.1672x; 1.0281x over previous
//
#include <hip/hip_runtime.h>
#include <math.h>

#define NN 8192
#define FF 128
#define CAP 128

typedef float nfloat4 __attribute__((ext_vector_type(4)));
typedef float nfloat2 __attribute__((ext_vector_type(2)));

__device__ __forceinline__ unsigned short f2bf(float f) {
  unsigned u = __float_as_uint(f);
  return (unsigned short)((u + 0x7fffu + ((u >> 16) & 1u)) >> 16);
}

// --- per-row dots f1,f2 + bf16-packed x table (features 2*lane, 2*lane+1)
__global__ __launch_bounds__(256) void k_scores(const float* __restrict__ x,
                                                const float* __restrict__ a,
                                                float* __restrict__ f1,
                                                float* __restrict__ f2,
                                                unsigned* __restrict__ xb) {
  const int w = threadIdx.x >> 6;
  const int lane = threadIdx.x & 63;
  const int row = blockIdx.x * 4 + w;
  float2 v = ((const float2*)(x + (size_t)row * FF))[lane];
  float2 A1 = ((const float2*)a)[lane];
  float2 A2 = ((const float2*)(a + FF))[lane];
  float s1 = v.x * A1.x + v.y * A1.y;
  float s2 = v.x * A2.x + v.y * A2.y;
  #pragma unroll
  for (int off = 32; off > 0; off >>= 1) {
    s1 += __shfl_down(s1, off);
    s2 += __shfl_down(s2, off);
  }
  if (lane == 0) { f1[row] = s1; f2[row] = s2; }
  unsigned pk = (unsigned)f2bf(v.x) | ((unsigned)f2bf(v.y) << 16);
  xb[(size_t)row * 64 + lane] = pk;
}

// --- wave-per-row: stream adj row (plain cached loads), ballot compaction,
//     wave softmax, fused fwd SpMM over bf16 x table + forward lifting.
__global__ __launch_bounds__(256) void k_scanfwd(
    const float* __restrict__ adj, const float* __restrict__ x,
    const unsigned* __restrict__ xb,
    const float* __restrict__ f1g, const float* __restrict__ f2g,
    const float* __restrict__ temp,
    int* __restrict__ nnzg, int* __restrict__ colsg, float* __restrict__ valsg,
    float* __restrict__ rowsumg, float* __restrict__ featg,
    unsigned* __restrict__ featb) {
  const int w = threadIdx.x >> 6;
  const int lane = threadIdx.x & 63;
  const int row = blockIdx.x * 4 + w;

  __shared__ int   s_c[4][CAP];
  __shared__ float s_u[4][CAP];

  // ---- stream one 32KB row per wave; wave-local deterministic compaction ----
  const nfloat4* arow = (const nfloat4*)(adj + (size_t)row * NN);
  const unsigned long long lt = (1ull << lane) - 1ull;
  int run = 0;
  #pragma unroll 8
  for (int it = 0; it < 32; ++it) {
    nfloat4 v = arow[it * 64 + lane];          // A/B vs R9: no nontemporal
    bool c0 = v.x > 0.f, c1 = v.y > 0.f, c2 = v.z > 0.f, c3 = v.w > 0.f;
    unsigned long long b0 = __ballot(c0), b1 = __ballot(c1),
                       b2 = __ballot(c2), b3 = __ballot(c3);
    int pos = run + __popcll(b0 & lt) + __popcll(b1 & lt) +
                    __popcll(b2 & lt) + __popcll(b3 & lt);
    int j0 = (it * 64 + lane) * 4;
    if (c0) { if (pos < CAP) s_c[w][pos] = j0;     pos++; }
    if (c1) { if (pos < CAP) s_c[w][pos] = j0 + 1; pos++; }
    if (c2) { if (pos < CAP) s_c[w][pos] = j0 + 2; pos++; }
    if (c3) { if (pos < CAP) s_c[w][pos] = j0 + 3; pos++; }
    run += __popcll(b0) + __popcll(b1) + __popcll(b2) + __popcll(b3);
  }
  const int cnt = run < CAP ? run : CAP;

  // ---- wave softmax + rowsum + persist sparse row (same-wave LDS, no barrier) ----
  const float F1 = f1g[row];
  const int i0 = lane, i1 = lane + 64;
  int col0 = (i0 < cnt) ? s_c[w][i0] : 0;
  int col1 = (i1 < cnt) ? s_c[w][i1] : 0;
  float e0 = -INFINITY, e1 = -INFINITY;
  if (i0 < cnt) { float s = F1 + f2g[col0]; e0 = s > 0.f ? s : 0.2f * s; }
  if (i1 < cnt) { float s = F1 + f2g[col1]; e1 = s > 0.f ? s : 0.2f * s; }
  float mx = fmaxf(e0, e1);
  #pragma unroll
  for (int off = 32; off > 0; off >>= 1) mx = fmaxf(mx, __shfl_xor(mx, off));
  float p0 = (i0 < cnt) ? expf(e0 - mx) : 0.f;
  float p1 = (i1 < cnt) ? expf(e1 - mx) : 0.f;
  float sm = p0 + p1;
  #pragma unroll
  for (int off = 32; off > 0; off >>= 1) sm += __shfl_xor(sm, off);
  float inv = 1.f / sm;
  float u0 = p0 * inv, u1 = p1 * inv;
  float q = u0 * u0 + u1 * u1;
  #pragma unroll
  for (int off = 32; off > 0; off >>= 1) q += __shfl_xor(q, off);
  const float rs = 0.5f * q;

  if (i0 < cnt) { s_u[w][i0] = u0; colsg[(size_t)row * CAP + i0] = col0;
                  valsg[(size_t)row * CAP + i0] = u0; }
  if (i1 < cnt) { s_u[w][i1] = u1; colsg[(size_t)row * CAP + i1] = col1;
                  valsg[(size_t)row * CAP + i1] = u1; }
  if (lane == 0) { nnzg[row] = cnt; rowsumg[row] = rs; }

  // ---- fwd SpMM over bf16 x table: 8 gathers (one uint each) in flight ----
  float acc0 = 0.f, acc1 = 0.f;
  int k = 0;
  for (; k + 7 < cnt; k += 8) {
    int   c0 = s_c[w][k],   c1 = s_c[w][k+1], c2 = s_c[w][k+2], c3 = s_c[w][k+3];
    int   c4 = s_c[w][k+4], c5 = s_c[w][k+5], c6 = s_c[w][k+6], c7 = s_c[w][k+7];
    float w0 = s_u[w][k],   w1 = s_u[w][k+1], w2 = s_u[w][k+2], w3 = s_u[w][k+3];
    float w4 = s_u[w][k+4], w5 = s_u[w][k+5], w6 = s_u[w][k+6], w7 = s_u[w][k+7];
    unsigned g0 = xb[(size_t)c0 * 64 + lane], g1 = xb[(size_t)c1 * 64 + lane];
    unsigned g2 = xb[(size_t)c2 * 64 + lane], g3 = xb[(size_t)c3 * 64 + lane];
    unsigned g4 = xb[(size_t)c4 * 64 + lane], g5 = xb[(size_t)c5 * 64 + lane];
    unsigned g6 = xb[(size_t)c6 * 64 + lane], g7 = xb[(size_t)c7 * 64 + lane];
    acc0 += w0 * __uint_as_float(g0 << 16) + w1 * __uint_as_float(g1 << 16)
          + w2 * __uint_as_float(g2 << 16) + w3 * __uint_as_float(g3 << 16)
          + w4 * __uint_as_float(g4 << 16) + w5 * __uint_as_float(g5 << 16)
          + w6 * __uint_as_float(g6 << 16) + w7 * __uint_as_float(g7 << 16);
    acc1 += w0 * __uint_as_float(g0 & 0xffff0000u) + w1 * __uint_as_float(g1 & 0xffff0000u)
          + w2 * __uint_as_float(g2 & 0xffff0000u) + w3 * __uint_as_float(g3 & 0xffff0000u)
          + w4 * __uint_as_float(g4 & 0xffff0000u) + w5 * __uint_as_float(g5 & 0xffff0000u)
          + w6 * __uint_as_float(g6 & 0xffff0000u) + w7 * __uint_as_float(g7 & 0xffff0000u);
  }
  for (; k < cnt; ++k) {
    int c = s_c[w][k]; float u = s_u[w][k];
    unsigned g = xb[(size_t)c * 64 + lane];
    acc0 += u * __uint_as_float(g << 16);
    acc1 += u * __uint_as_float(g & 0xffff0000u);
  }

  const float coe2 = 1.f / (1.f + expf(-temp[2]));
  float2 xv = ((const float2*)(x + (size_t)row * FF))[lane];
  float ft0 = acc0 - xv.x * rs + (1.f - coe2) * xv.x;
  float ft1 = acc1 - xv.y * rs + (1.f - coe2) * xv.y;
  float2 ftv; ftv.x = ft0; ftv.y = ft1;
  ((float2*)featg)[(size_t)row * 64 + lane] = ftv;
  featb[(size_t)row * 64 + lane] = (unsigned)f2bf(ft0) | ((unsigned)f2bf(ft1) << 16);
}

// --- wave-per-row: SpMM U@feat (bf16 table) + inverse lifting + blend
__global__ __launch_bounds__(256) void k_bwd(
    const float* __restrict__ featg, const unsigned* __restrict__ featb,
    const float* __restrict__ h0, const float* __restrict__ temp,
    const int* __restrict__ nnzg, const int* __restrict__ colsg,
    const float* __restrict__ valsg, const float* __restrict__ rowsumg,
    float* __restrict__ out) {
  const int w = threadIdx.x >> 6;
  const int lane = threadIdx.x & 63;
  const int row = blockIdx.x * 4 + w;

  __shared__ int   s_c[4][CAP];
  __shared__ float s_u[4][CAP];

  const int cnt = nnzg[row];
  const int* cg = colsg + (size_t)row * CAP;
  const float* vg = valsg + (size_t)row * CAP;
  const int i0 = lane, i1 = lane + 64;
  if (i0 < cnt) { s_c[w][i0] = cg[i0]; s_u[w][i0] = vg[i0]; }
  if (i1 < cnt) { s_c[w][i1] = cg[i1]; s_u[w][i1] = vg[i1]; }

  float acc0 = 0.f, acc1 = 0.f;
  int k = 0;
  for (; k + 7 < cnt; k += 8) {
    int   c0 = s_c[w][k],   c1 = s_c[w][k+1], c2 = s_c[w][k+2], c3 = s_c[w][k+3];
    int   c4 = s_c[w][k+4], c5 = s_c[w][k+5], c6 = s_c[w][k+6], c7 = s_c[w][k+7];
    float w0 = s_u[w][k],   w1 = s_u[w][k+1], w2 = s_u[w][k+2], w3 = s_u[w][k+3];
    float w4 = s_u[w][k+4], w5 = s_u[w][k+5], w6 = s_u[w][k+6], w7 = s_u[w][k+7];
    unsigned g0 = featb[(size_t)c0 * 64 + lane], g1 = featb[(size_t)c1 * 64 + lane];
    unsigned g2 = featb[(size_t)c2 * 64 + lane], g3 = featb[(size_t)c3 * 64 + lane];
    unsigned g4 = featb[(size_t)c4 * 64 + lane], g5 = featb[(size_t)c5 * 64 + lane];
    unsigned g6 = featb[(size_t)c6 * 64 + lane], g7 = featb[(size_t)c7 * 64 + lane];
    acc0 += w0 * __uint_as_float(g0 << 16) + w1 * __uint_as_float(g1 << 16)
          + w2 * __uint_as_float(g2 << 16) + w3 * __uint_as_float(g3 << 16)
          + w4 * __uint_as_float(g4 << 16) + w5 * __uint_as_float(g5 << 16)
          + w6 * __uint_as_float(g6 << 16) + w7 * __uint_as_float(g7 << 16);
    acc1 += w0 * __uint_as_float(g0 & 0xffff0000u) + w1 * __uint_as_float(g1 & 0xffff0000u)
          + w2 * __uint_as_float(g2 & 0xffff0000u) + w3 * __uint_as_float(g3 & 0xffff0000u)
          + w4 * __uint_as_float(g4 & 0xffff0000u) + w5 * __uint_as_float(g5 & 0xffff0000u)
          + w6 * __uint_as_float(g6 & 0xffff0000u) + w7 * __uint_as_float(g7 & 0xffff0000u);
  }
  for (; k < cnt; ++k) {
    int c = s_c[w][k]; float u = s_u[w][k];
    unsigned g = featb[(size_t)c * 64 + lane];
    acc0 += u * __uint_as_float(g << 16);
    acc1 += u * __uint_as_float(g & 0xffff0000u);
  }

  const float rs = rowsumg[row];
  const float coe1 = 1.f / (1.f + expf(-temp[1]));
  const float coe3 = 1.f / (1.f + expf(-temp[3]));
  float2 ft = ((const float2*)featg)[(size_t)row * 64 + lane];
  float odd0 = ft.x - acc0, odd1 = ft.y - acc1;
  float ev0 = coe3 * acc0 + odd0 * rs;
  float ev1 = coe3 * acc1 + odd1 * rs;
  float fp0 = coe1 * ev0 + (1.f - coe1) * odd0;
  float fp1 = coe1 * ev1 + (1.f - coe1) * odd1;
  nfloat2 h = __builtin_nontemporal_load(((const nfloat2*)h0) + (size_t)row * 64 + lane);
  nfloat2 o;
  o.x = 0.2f * fp0 + 0.8f * h.x;
  o.y = 0.2f * fp1 + 0.8f * h.y;
  __builtin_nontemporal_store(o, ((nfloat2*)out) + (size_t)row * 64 + lane);
}

extern "C" void kernel_launch(void* const* d_in, const int* in_sizes, int n_in,
                              void* d_out, int out_size, void* d_ws, size_t ws_size,
                              hipStream_t stream) {
  const float* x    = (const float*)d_in[0];
  const float* h0   = (const float*)d_in[1];
  const float* adj  = (const float*)d_in[2];
  const float* a    = (const float*)d_in[3];
  const float* temp = (const float*)d_in[4];
  float* out = (float*)d_out;

  float* f1 = (float*)d_ws;                       // 32 KB
  float* f2 = f1 + NN;                            // 32 KB
  float* rowsum = f2 + NN;                        // 32 KB
  int*   nnz = (int*)(rowsum + NN);               // 32 KB
  int*   cols = nnz + NN;                         // 4 MB
  float* vals = (float*)(cols + (size_t)NN * CAP);// 4 MB
  float* feat = vals + (size_t)NN * CAP;          // 4 MB
  unsigned* xb = (unsigned*)(feat + (size_t)NN * FF);   // 2 MB
  unsigned* featb = xb + (size_t)NN * 64;               // 2 MB

  k_scores<<<NN / 4, 256, 0, stream>>>(x, a, f1, f2, xb);
  k_scanfwd<<<NN / 4, 256, 0, stream>>>(adj, x, xb, f1, f2, temp, nnz, cols, vals, rowsum, feat, featb);
  k_bwd<<<NN / 4, 256, 0, stream>>>(feat, featb, h0, temp, nnz, cols, vals, rowsum, out);
}